// Round 4
// baseline (510.310 us; speedup 1.0000x reference)
//
#include <hip/hip_runtime.h>
#include <stdint.h>

// Problem constants (from reference)
#define N_NODES 16384
#define E_EDGES 524288
#define F_INF   128      // node feature dim
#define H_DIM   256      // hidden dim
#define A_DIM   64       // action size
#define WPR     (N_NODES / 32)   // bitmap words per row = 512

// ---------------- ws layout ----------------
#define BITMAP_BYTES ((size_t)N_NODES * WPR * 4)            // 33,554,432
#define GACC_OFF     BITMAP_BYTES
#define T_OFF        (BITMAP_BYTES + 1024)

// ---------------------------------------------------------------
// K1: scatter edges into dedupe bitmap. adj[src][dst] |= 1.
// ---------------------------------------------------------------
__global__ __launch_bounds__(256) void k_scatter(const int* __restrict__ ei,
                                                 uint32_t* __restrict__ bm) {
    int e = blockIdx.x * 256 + threadIdx.x;
    if (e < E_EDGES) {
        int s = ei[e];              // edge_index[0][e]
        int d = ei[E_EDGES + e];    // edge_index[1][e]
        atomicOr(&bm[(size_t)s * WPR + (d >> 5)], 1u << (d & 31));
    }
}

// ---------------------------------------------------------------
// K2: one wave per node. Scan bitmap row as uint4 (2 ballot rounds),
// gather X rows of unique neighbors (lane l owns feature elems
// 2l,2l+1 -> float2, 512B coalesced per row). deg = popcount + 1.
// ---------------------------------------------------------------
__global__ __launch_bounds__(256) void k_gather(const float* __restrict__ X,
                                                const uint32_t* __restrict__ bm,
                                                float* __restrict__ t) {
    int n    = blockIdx.x * 4 + (threadIdx.x >> 6);   // node = wave id
    int lane = threadIdx.x & 63;
    const uint4* row4 = (const uint4*)(bm + (size_t)n * WPR);  // 128 uint4

    float2 a = *(const float2*)(X + (size_t)n * F_INF + 2 * lane);
    int cnt = 1;                                      // eye contributes 1

    for (int base = 0; base < 128; base += 64) {      // 2 iterations
        uint4 b = row4[base + lane];
        unsigned long long nz = __ballot((b.x | b.y | b.z | b.w) != 0u);
        while (nz) {
            int l = __builtin_ctzll(nz);
            nz &= nz - 1;
            uint32_t w0 = (uint32_t)__shfl((int)b.x, l);
            uint32_t w1 = (uint32_t)__shfl((int)b.y, l);
            uint32_t w2 = (uint32_t)__shfl((int)b.z, l);
            uint32_t w3 = (uint32_t)__shfl((int)b.w, l);
            int dbase = (base + l) << 7;              // 128 bits per uint4
#pragma unroll
            for (int q = 0; q < 4; ++q) {
                uint32_t w = q == 0 ? w0 : (q == 1 ? w1 : (q == 2 ? w2 : w3));
                int db = dbase + (q << 5);
                while (w) {
                    int bpos = __builtin_ctz(w);
                    w &= w - 1;
                    int d = db + bpos;
                    float2 xv = *(const float2*)(X + (size_t)d * F_INF + 2 * lane);
                    a.x += xv.x;
                    a.y += xv.y;
                    ++cnt;
                }
            }
        }
    }
    float inv = 1.0f / (float)cnt;
    a.x *= inv; a.y *= inv;
    *(float2*)(t + (size_t)n * F_INF + 2 * lane) = a;
}

// ---------------------------------------------------------------
// K3: tiled SGEMM + fused relu/column-sum.
// C[j][n] = W[j]·t[n];  g_acc[j] += sum_n relu(C + b[j]).
// Block tile 64j x 64n, K=128 staged once. Thread tile 4j x 4n:
// j = j0 + ty + jj*16, n = n0 + tx + nn*16  (ty=tid>>4, tx=tid&15).
// LDS rows padded to 132 floats: per-instr wave addresses analyzed
// <=2-way bank aliasing (free). Each ds_read_b128 feeds 8 FMAs.
// Epilogue: relu, shfl-reduce over tx (lane bits 0-3), 64 atomics/block.
// Block remap keeps the 4 j-tiles of one n-tile on one XCD.
// ---------------------------------------------------------------
#define LDS_STRIDE 132
__global__ __launch_bounds__(256) void k_gemm(const float* __restrict__ t,
                                              const float* __restrict__ Wg,
                                              const float* __restrict__ bg,
                                              float* __restrict__ g_accum) {
    __shared__ __align__(16) float Wl[64 * LDS_STRIDE];   // 33.8 KB
    __shared__ __align__(16) float Tl[64 * LDS_STRIDE];   // 33.8 KB

    int tid = threadIdx.x;
    int bid = blockIdx.x;
    // XCD-contiguous remap: 1024 blocks, 8 XCDs, 128 blocks each.
    int v  = (bid >> 3) + (bid & 7) * 128;
    int jt = v & 3, nt = v >> 2;
    int j0 = jt * 64, n0 = nt * 64;

    // cooperative coalesced stage of both tiles (8 rows per pass)
#pragma unroll
    for (int i = tid; i < 64 * 32; i += 256) {
        int r = i >> 5, c = i & 31;
        ((float4*)(Wl + r * LDS_STRIDE))[c] =
            ((const float4*)(Wg + (size_t)(j0 + r) * F_INF))[c];
        ((float4*)(Tl + r * LDS_STRIDE))[c] =
            ((const float4*)(t + (size_t)(n0 + r) * F_INF))[c];
    }

    int ty = tid >> 4, tx = tid & 15;
    float bj[4];
#pragma unroll
    for (int jj = 0; jj < 4; ++jj) bj[jj] = bg[j0 + ty + jj * 16];

    __syncthreads();

    float acc[4][4];
#pragma unroll
    for (int jj = 0; jj < 4; ++jj)
#pragma unroll
        for (int nn = 0; nn < 4; ++nn) acc[jj][nn] = 0.0f;

#pragma unroll
    for (int kk = 0; kk < 32; ++kk) {
        int k = kk * 4;
        float4 w[4], v4[4];
#pragma unroll
        for (int jj = 0; jj < 4; ++jj)
            w[jj] = *(const float4*)(Wl + (ty + jj * 16) * LDS_STRIDE + k);
#pragma unroll
        for (int nn = 0; nn < 4; ++nn)
            v4[nn] = *(const float4*)(Tl + (tx + nn * 16) * LDS_STRIDE + k);
#pragma unroll
        for (int jj = 0; jj < 4; ++jj)
#pragma unroll
            for (int nn = 0; nn < 4; ++nn)
                acc[jj][nn] += w[jj].x * v4[nn].x + w[jj].y * v4[nn].y +
                               w[jj].z * v4[nn].z + w[jj].w * v4[nn].w;
    }

    // epilogue: relu + sum over this thread's 4 n, reduce over tx, atomic
#pragma unroll
    for (int jj = 0; jj < 4; ++jj) {
        float s = 0.0f;
#pragma unroll
        for (int nn = 0; nn < 4; ++nn) s += fmaxf(acc[jj][nn] + bj[jj], 0.0f);
        s += __shfl_xor(s, 1);
        s += __shfl_xor(s, 2);
        s += __shfl_xor(s, 4);
        s += __shfl_xor(s, 8);
        if (tx == 0) atomicAdd(&g_accum[j0 + ty + jj * 16], s);
    }
}

// ---------------------------------------------------------------
// K4: heads. g = g_accum/N; actor & critic MLPs; softmax; value.
// ---------------------------------------------------------------
__global__ __launch_bounds__(256) void k_heads(const float* __restrict__ g_accum,
                                               const float* __restrict__ W_a1,
                                               const float* __restrict__ b_a1,
                                               const float* __restrict__ W_a2,
                                               const float* __restrict__ b_a2,
                                               const float* __restrict__ W_c1,
                                               const float* __restrict__ b_c1,
                                               const float* __restrict__ W_c2,
                                               const float* __restrict__ b_c2,
                                               float* __restrict__ out) {
    __shared__ float gv[H_DIM];
    __shared__ float ah[128];   // actor hidden
    __shared__ float ch[128];   // critic hidden
    int tid = threadIdx.x;

    gv[tid] = g_accum[tid] * (1.0f / (float)N_NODES);
    __syncthreads();

    if (tid < 128) {
        float acc = b_a1[tid];
        const float* wr = W_a1 + tid * H_DIM;
        for (int k = 0; k < H_DIM; ++k) acc += wr[k] * gv[k];
        ah[tid] = fmaxf(acc, 0.0f);
    } else {
        int i = tid - 128;
        float acc = b_c1[i];
        const float* wr = W_c1 + i * H_DIM;
        for (int k = 0; k < H_DIM; ++k) acc += wr[k] * gv[k];
        ch[i] = fmaxf(acc, 0.0f);
    }
    __syncthreads();

    if (tid < 64) {
        float acc = b_a2[tid];
        const float* wr = W_a2 + tid * 128;
        for (int i = 0; i < 128; ++i) acc += wr[i] * ah[i];
        float m = acc;
        for (int off = 32; off; off >>= 1) m = fmaxf(m, __shfl_xor(m, off));
        float e = expf(acc - m);
        float s = e;
        for (int off = 32; off; off >>= 1) s += __shfl_xor(s, off);
        out[tid] = e / s;
    } else if (tid < 128) {
        int l = tid - 64;
        float acc = 0.0f;
        for (int i = l; i < 128; i += 64) acc += W_c2[i] * ch[i];
        for (int off = 32; off; off >>= 1) acc += __shfl_xor(acc, off);
        if (l == 0) out[A_DIM] = acc + b_c2[0];
    }
}

// ---------------------------------------------------------------
extern "C" void kernel_launch(void* const* d_in, const int* in_sizes, int n_in,
                              void* d_out, int out_size, void* d_ws, size_t ws_size,
                              hipStream_t stream) {
    const float* X    = (const float*)d_in[0];
    const int*   ei   = (const int*)d_in[1];
    const float* Wg   = (const float*)d_in[2];
    const float* bg   = (const float*)d_in[3];
    const float* W_a1 = (const float*)d_in[4];
    const float* b_a1 = (const float*)d_in[5];
    const float* W_a2 = (const float*)d_in[6];
    const float* b_a2 = (const float*)d_in[7];
    const float* W_c1 = (const float*)d_in[8];
    const float* b_c1 = (const float*)d_in[9];
    const float* W_c2 = (const float*)d_in[10];
    const float* b_c2 = (const float*)d_in[11];
    float* out = (float*)d_out;

    uint8_t*  ws     = (uint8_t*)d_ws;
    uint32_t* bitmap = (uint32_t*)ws;
    float*    g_acc  = (float*)(ws + GACC_OFF);
    float*    t      = (float*)(ws + T_OFF);

    hipMemsetAsync(d_ws, 0, BITMAP_BYTES + 1024, stream);

    k_scatter<<<E_EDGES / 256, 256, 0, stream>>>(ei, bitmap);
    k_gather <<<N_NODES / 4, 256, 0, stream>>>(X, bitmap, t);
    k_gemm   <<<1024, 256, 0, stream>>>(t, Wg, bg, g_acc);
    k_heads  <<<1, 256, 0, stream>>>(g_acc, W_a1, b_a1, W_a2, b_a2,
                                     W_c1, b_c1, W_c2, b_c2, out);
}

// Round 6
// 202.545 us; speedup vs baseline: 2.5195x; 2.5195x over previous
//
#include <hip/hip_runtime.h>
#include <stdint.h>

// Problem constants (from reference)
#define N_NODES 16384
#define E_EDGES 524288
#define F_INF   128      // node feature dim
#define H_DIM   256      // hidden dim
#define A_DIM   64       // action size
#define WPR     (N_NODES / 32)   // bitmap words per row = 512

// ---------------- ws layout ----------------
#define BITMAP_BYTES ((size_t)N_NODES * WPR * 4)            // 33,554,432
#define GACC_OFF     BITMAP_BYTES
#define T_OFF        (BITMAP_BYTES + 1024)

// ---------------------------------------------------------------
// K1: scatter edges into dedupe bitmap. adj[src][dst] |= 1.
// ---------------------------------------------------------------
__global__ __launch_bounds__(256) void k_scatter(const int* __restrict__ ei,
                                                 uint32_t* __restrict__ bm) {
    int e = blockIdx.x * 256 + threadIdx.x;
    if (e < E_EDGES) {
        int s = ei[e];              // edge_index[0][e]
        int d = ei[E_EDGES + e];    // edge_index[1][e]
        atomicOr(&bm[(size_t)s * WPR + (d >> 5)], 1u << (d & 31));
    }
}

// ---------------------------------------------------------------
// K2: one wave per node. Scan bitmap row as uint4 (2 ballot rounds),
// gather X rows of unique neighbors (lane l owns feature elems
// 2l,2l+1 -> float2, 512B coalesced per row). deg = popcount + 1.
// ---------------------------------------------------------------
__global__ __launch_bounds__(256) void k_gather(const float* __restrict__ X,
                                                const uint32_t* __restrict__ bm,
                                                float* __restrict__ t) {
    int n    = blockIdx.x * 4 + (threadIdx.x >> 6);   // node = wave id
    int lane = threadIdx.x & 63;
    const uint4* row4 = (const uint4*)(bm + (size_t)n * WPR);  // 128 uint4

    float2 a = *(const float2*)(X + (size_t)n * F_INF + 2 * lane);
    int cnt = 1;                                      // eye contributes 1

    for (int base = 0; base < 128; base += 64) {      // 2 iterations
        uint4 b = row4[base + lane];
        unsigned long long nz = __ballot((b.x | b.y | b.z | b.w) != 0u);
        while (nz) {
            int l = __builtin_ctzll(nz);
            nz &= nz - 1;
            uint32_t w0 = (uint32_t)__shfl((int)b.x, l);
            uint32_t w1 = (uint32_t)__shfl((int)b.y, l);
            uint32_t w2 = (uint32_t)__shfl((int)b.z, l);
            uint32_t w3 = (uint32_t)__shfl((int)b.w, l);
            int dbase = (base + l) << 7;              // 128 bits per uint4
#pragma unroll
            for (int q = 0; q < 4; ++q) {
                uint32_t w = q == 0 ? w0 : (q == 1 ? w1 : (q == 2 ? w2 : w3));
                int db = dbase + (q << 5);
                while (w) {
                    int bpos = __builtin_ctz(w);
                    w &= w - 1;
                    int d = db + bpos;
                    float2 xv = *(const float2*)(X + (size_t)d * F_INF + 2 * lane);
                    a.x += xv.x;
                    a.y += xv.y;
                    ++cnt;
                }
            }
        }
    }
    float inv = 1.0f / (float)cnt;
    a.x *= inv; a.y *= inv;
    *(float2*)(t + (size_t)n * F_INF + 2 * lane) = a;
}

// ---------------------------------------------------------------
// K3: tiled SGEMM + fused relu/column-sum.
// C[j][n] = W[j]·t[n];  g_acc[j] += sum_n relu(C + b[j]).
// Block tile 64j x 64n, K=128 staged once. Thread tile 4j x 4n.
// *** #pragma unroll 2 on the K loop is load-pressure control: R4's
// full unroll let the scheduler hoist all 256 ds_reads -> 256 VGPR,
// ~940MB scratch spill traffic, 354us. Window of 2 keeps <=16 live
// float4 loads (~110 VGPR total). ***
// LDS rows padded to 132 floats (<=2-way bank aliasing = free).
// Epilogue: relu, shfl-reduce over tx, 64 atomics/block.
// ---------------------------------------------------------------
#define LDS_STRIDE 132
__global__ __launch_bounds__(256, 2) void k_gemm(const float* __restrict__ t,
                                                 const float* __restrict__ Wg,
                                                 const float* __restrict__ bg,
                                                 float* __restrict__ g_accum) {
    __shared__ __align__(16) float Wl[64 * LDS_STRIDE];   // 33.8 KB
    __shared__ __align__(16) float Tl[64 * LDS_STRIDE];   // 33.8 KB

    int tid = threadIdx.x;
    int bid = blockIdx.x;
    // XCD-contiguous remap: 1024 blocks, 8 XCDs, 128 blocks each.
    int v  = (bid >> 3) + (bid & 7) * 128;
    int jt = v & 3, nt = v >> 2;
    int j0 = jt * 64, n0 = nt * 64;

    // cooperative coalesced stage of both tiles
#pragma unroll
    for (int i = tid; i < 64 * 32; i += 256) {
        int r = i >> 5, c = i & 31;
        ((float4*)(Wl + r * LDS_STRIDE))[c] =
            ((const float4*)(Wg + (size_t)(j0 + r) * F_INF))[c];
        ((float4*)(Tl + r * LDS_STRIDE))[c] =
            ((const float4*)(t + (size_t)(n0 + r) * F_INF))[c];
    }

    int ty = tid >> 4, tx = tid & 15;
    float bj[4];
#pragma unroll
    for (int jj = 0; jj < 4; ++jj) bj[jj] = bg[j0 + ty + jj * 16];

    __syncthreads();

    float acc[4][4];
#pragma unroll
    for (int jj = 0; jj < 4; ++jj)
#pragma unroll
        for (int nn = 0; nn < 4; ++nn) acc[jj][nn] = 0.0f;

#pragma unroll 2
    for (int kk = 0; kk < 32; ++kk) {
        int k = kk * 4;
        float4 w[4], v4[4];
#pragma unroll
        for (int jj = 0; jj < 4; ++jj)
            w[jj] = *(const float4*)(Wl + (ty + jj * 16) * LDS_STRIDE + k);
#pragma unroll
        for (int nn = 0; nn < 4; ++nn)
            v4[nn] = *(const float4*)(Tl + (tx + nn * 16) * LDS_STRIDE + k);
#pragma unroll
        for (int jj = 0; jj < 4; ++jj)
#pragma unroll
            for (int nn = 0; nn < 4; ++nn)
                acc[jj][nn] += w[jj].x * v4[nn].x + w[jj].y * v4[nn].y +
                               w[jj].z * v4[nn].z + w[jj].w * v4[nn].w;
    }

    // epilogue: relu + sum over this thread's 4 n, reduce over tx, atomic
#pragma unroll
    for (int jj = 0; jj < 4; ++jj) {
        float s = 0.0f;
#pragma unroll
        for (int nn = 0; nn < 4; ++nn) s += fmaxf(acc[jj][nn] + bj[jj], 0.0f);
        s += __shfl_xor(s, 1);
        s += __shfl_xor(s, 2);
        s += __shfl_xor(s, 4);
        s += __shfl_xor(s, 8);
        if (tx == 0) atomicAdd(&g_accum[j0 + ty + jj * 16], s);
    }
}

// ---------------------------------------------------------------
// K4: heads. g = g_accum/N; actor & critic MLPs; softmax; value.
// ---------------------------------------------------------------
__global__ __launch_bounds__(256) void k_heads(const float* __restrict__ g_accum,
                                               const float* __restrict__ W_a1,
                                               const float* __restrict__ b_a1,
                                               const float* __restrict__ W_a2,
                                               const float* __restrict__ b_a2,
                                               const float* __restrict__ W_c1,
                                               const float* __restrict__ b_c1,
                                               const float* __restrict__ W_c2,
                                               const float* __restrict__ b_c2,
                                               float* __restrict__ out) {
    __shared__ float gv[H_DIM];
    __shared__ float ah[128];   // actor hidden
    __shared__ float ch[128];   // critic hidden
    int tid = threadIdx.x;

    gv[tid] = g_accum[tid] * (1.0f / (float)N_NODES);
    __syncthreads();

    if (tid < 128) {
        float acc = b_a1[tid];
        const float* wr = W_a1 + tid * H_DIM;
        for (int k = 0; k < H_DIM; ++k) acc += wr[k] * gv[k];
        ah[tid] = fmaxf(acc, 0.0f);
    } else {
        int i = tid - 128;
        float acc = b_c1[i];
        const float* wr = W_c1 + i * H_DIM;
        for (int k = 0; k < H_DIM; ++k) acc += wr[k] * gv[k];
        ch[i] = fmaxf(acc, 0.0f);
    }
    __syncthreads();

    if (tid < 64) {
        float acc = b_a2[tid];
        const float* wr = W_a2 + tid * 128;
        for (int i = 0; i < 128; ++i) acc += wr[i] * ah[i];
        float m = acc;
        for (int off = 32; off; off >>= 1) m = fmaxf(m, __shfl_xor(m, off));
        float e = expf(acc - m);
        float s = e;
        for (int off = 32; off; off >>= 1) s += __shfl_xor(s, off);
        out[tid] = e / s;
    } else if (tid < 128) {
        int l = tid - 64;
        float acc = 0.0f;
        for (int i = l; i < 128; i += 64) acc += W_c2[i] * ch[i];
        for (int off = 32; off; off >>= 1) acc += __shfl_xor(acc, off);
        if (l == 0) out[A_DIM] = acc + b_c2[0];
    }
}

// ---------------------------------------------------------------
extern "C" void kernel_launch(void* const* d_in, const int* in_sizes, int n_in,
                              void* d_out, int out_size, void* d_ws, size_t ws_size,
                              hipStream_t stream) {
    const float* X    = (const float*)d_in[0];
    const int*   ei   = (const int*)d_in[1];
    const float* Wg   = (const float*)d_in[2];
    const float* bg   = (const float*)d_in[3];
    const float* W_a1 = (const float*)d_in[4];
    const float* b_a1 = (const float*)d_in[5];
    const float* W_a2 = (const float*)d_in[6];
    const float* b_a2 = (const float*)d_in[7];
    const float* W_c1 = (const float*)d_in[8];
    const float* b_c1 = (const float*)d_in[9];
    const float* W_c2 = (const float*)d_in[10];
    const float* b_c2 = (const float*)d_in[11];
    float* out = (float*)d_out;

    uint8_t*  ws     = (uint8_t*)d_ws;
    uint32_t* bitmap = (uint32_t*)ws;
    float*    g_acc  = (float*)(ws + GACC_OFF);
    float*    t      = (float*)(ws + T_OFF);

    hipMemsetAsync(d_ws, 0, BITMAP_BYTES + 1024, stream);

    k_scatter<<<E_EDGES / 256, 256, 0, stream>>>(ei, bitmap);
    k_gather <<<N_NODES / 4, 256, 0, stream>>>(X, bitmap, t);
    k_gemm   <<<1024, 256, 0, stream>>>(t, Wg, bg, g_acc);
    k_heads  <<<1, 256, 0, stream>>>(g_acc, W_a1, b_a1, W_a2, b_a2,
                                     W_c1, b_c1, W_c2, b_c2, out);
}

// Round 7
// 188.056 us; speedup vs baseline: 2.7136x; 1.0770x over previous
//
#include <hip/hip_runtime.h>
#include <stdint.h>

// Problem constants (from reference)
#define N_NODES 16384
#define E_EDGES 524288
#define F_INF   128      // node feature dim
#define H_DIM   256      // hidden dim
#define A_DIM   64       // action size
#define WPR     (N_NODES / 32)   // bitmap words per row = 512

// ---------------- ws layout ----------------
#define BITMAP_BYTES ((size_t)N_NODES * WPR * 4)            // 33,554,432
#define GACC_OFF     BITMAP_BYTES
#define T_OFF        (BITMAP_BYTES + 1024)

// ---------------------------------------------------------------
// K1: scatter edges into dedupe bitmap. adj[src][dst] |= 1.
// ---------------------------------------------------------------
__global__ __launch_bounds__(256) void k_scatter(const int* __restrict__ ei,
                                                 uint32_t* __restrict__ bm) {
    int e = blockIdx.x * 256 + threadIdx.x;
    if (e < E_EDGES) {
        int s = ei[e];              // edge_index[0][e]
        int d = ei[E_EDGES + e];    // edge_index[1][e]
        atomicOr(&bm[(size_t)s * WPR + (d >> 5)], 1u << (d & 31));
    }
}

// ---------------------------------------------------------------
// K2 (rewritten): one wave per node, two phases.
// Phase A: scan bitmap row (128 uint4), per-lane popcount +
//   shfl_up prefix-sum -> each lane writes its set-bit indices
//   (uint16 node ids) into a per-wave LDS queue. No per-neighbor
//   shfl broadcasts (R6 evidence: 4 shfl/neighbor + dependent
//   loads = 48.6us, VALUBusy 28%). deg = 1 + popcount total.
// Phase B: walk the flat queue 8 at a time -> 8 INDEPENDENT
//   float2 gathers (MLP=8), tree-summed. HBM-BW-bound (~88MB).
// QCAP 2048/wave: max degree is Poisson(32); writes clamped for
// memory safety in the impossible overflow case.
// ---------------------------------------------------------------
#define QCAP 2048
__global__ __launch_bounds__(256) void k_gather(const float* __restrict__ X,
                                                const uint32_t* __restrict__ bm,
                                                float* __restrict__ t) {
    __shared__ uint16_t q[4][QCAP];             // 16 KB/block
    int n    = blockIdx.x * 4 + (threadIdx.x >> 6);
    int lane = threadIdx.x & 63;
    int wid  = threadIdx.x >> 6;
    uint16_t* myq = q[wid];
    const uint4* row4 = (const uint4*)(bm + (size_t)n * WPR);  // 128 uint4
    const float2* X2 = (const float2*)X;

    // ---- Phase A: compact set bits into LDS queue ----
    int nw = 0;
#pragma unroll
    for (int r = 0; r < 2; ++r) {
        uint4 b = row4[r * 64 + lane];
        int tb = __popc(b.x) + __popc(b.y) + __popc(b.z) + __popc(b.w);
        int incl = tb;
#pragma unroll
        for (int off = 1; off < 64; off <<= 1) {
            int tprev = __shfl_up(incl, off);
            if (lane >= off) incl += tprev;
        }
        int pos   = nw + incl - tb;             // exclusive prefix
        int total = __shfl(incl, 63);
        int wbase = (r * 64 + lane) * 4;        // word index of b.x
#define EXPAND(word, widx) { uint32_t w_ = (word); int db_ = (widx) << 5;      \
        while (w_) { int b_ = __builtin_ctz(w_); w_ &= w_ - 1;                 \
            myq[pos < QCAP ? pos : QCAP - 1] = (uint16_t)(db_ + b_); ++pos; } }
        EXPAND(b.x, wbase)
        EXPAND(b.y, wbase + 1)
        EXPAND(b.z, wbase + 2)
        EXPAND(b.w, wbase + 3)
#undef EXPAND
        nw += total;
    }
    __syncthreads();   // order Phase A LDS writes before Phase B reads

    // ---- Phase B: batched gather, MLP=8 ----
    float2 a = X2[(size_t)n * 64 + lane];       // identity term
    int cnt = 1 + nw;                           // deg = eye + unique neighbors

    const uint64_t* q8 = (const uint64_t*)myq;  // 4 uint16 ids per read
    int i = 0;
    for (; i + 8 <= nw; i += 8) {
        uint64_t p0 = q8[(i >> 2)];
        uint64_t p1 = q8[(i >> 2) + 1];
        int d0 = (int)(p0 & 0xFFFF), d1 = (int)((p0 >> 16) & 0xFFFF);
        int d2 = (int)((p0 >> 32) & 0xFFFF), d3 = (int)(p0 >> 48);
        int d4 = (int)(p1 & 0xFFFF), d5 = (int)((p1 >> 16) & 0xFFFF);
        int d6 = (int)((p1 >> 32) & 0xFFFF), d7 = (int)(p1 >> 48);
        float2 v0 = X2[(size_t)d0 * 64 + lane];
        float2 v1 = X2[(size_t)d1 * 64 + lane];
        float2 v2 = X2[(size_t)d2 * 64 + lane];
        float2 v3 = X2[(size_t)d3 * 64 + lane];
        float2 v4 = X2[(size_t)d4 * 64 + lane];
        float2 v5 = X2[(size_t)d5 * 64 + lane];
        float2 v6 = X2[(size_t)d6 * 64 + lane];
        float2 v7 = X2[(size_t)d7 * 64 + lane];
        float sx = ((v0.x + v1.x) + (v2.x + v3.x)) + ((v4.x + v5.x) + (v6.x + v7.x));
        float sy = ((v0.y + v1.y) + (v2.y + v3.y)) + ((v4.y + v5.y) + (v6.y + v7.y));
        a.x += sx;
        a.y += sy;
    }
    for (; i < nw; ++i) {
        int d = myq[i];
        float2 v = X2[(size_t)d * 64 + lane];
        a.x += v.x;
        a.y += v.y;
    }

    float inv = 1.0f / (float)cnt;
    float2 r;
    r.x = a.x * inv;
    r.y = a.y * inv;
    ((float2*)t)[(size_t)n * 64 + lane] = r;
}

// ---------------------------------------------------------------
// K3: tiled SGEMM + fused relu/column-sum.
// C[j][n] = W[j]·t[n];  g_acc[j] += sum_n relu(C + b[j]).
// Block tile 64j x 64n, K=128 staged once. Thread tile 4j x 4n.
// *** #pragma unroll 2 on the K loop is load-pressure control: R4's
// full unroll let the scheduler hoist all 256 ds_reads -> 256 VGPR,
// ~940MB scratch spill traffic, 354us. Window of 2 keeps <=16 live
// float4 loads. R6: dropped out of top-5 (<48us). ***
// LDS rows padded to 132 floats (<=2-way bank aliasing = free).
// Epilogue: relu, shfl-reduce over tx, 64 atomics/block.
// ---------------------------------------------------------------
#define LDS_STRIDE 132
__global__ __launch_bounds__(256, 2) void k_gemm(const float* __restrict__ t,
                                                 const float* __restrict__ Wg,
                                                 const float* __restrict__ bg,
                                                 float* __restrict__ g_accum) {
    __shared__ __align__(16) float Wl[64 * LDS_STRIDE];   // 33.8 KB
    __shared__ __align__(16) float Tl[64 * LDS_STRIDE];   // 33.8 KB

    int tid = threadIdx.x;
    int bid = blockIdx.x;
    // XCD-contiguous remap: 1024 blocks, 8 XCDs, 128 blocks each.
    int v  = (bid >> 3) + (bid & 7) * 128;
    int jt = v & 3, nt = v >> 2;
    int j0 = jt * 64, n0 = nt * 64;

    // cooperative coalesced stage of both tiles
#pragma unroll
    for (int i = tid; i < 64 * 32; i += 256) {
        int r = i >> 5, c = i & 31;
        ((float4*)(Wl + r * LDS_STRIDE))[c] =
            ((const float4*)(Wg + (size_t)(j0 + r) * F_INF))[c];
        ((float4*)(Tl + r * LDS_STRIDE))[c] =
            ((const float4*)(t + (size_t)(n0 + r) * F_INF))[c];
    }

    int ty = tid >> 4, tx = tid & 15;
    float bj[4];
#pragma unroll
    for (int jj = 0; jj < 4; ++jj) bj[jj] = bg[j0 + ty + jj * 16];

    __syncthreads();

    float acc[4][4];
#pragma unroll
    for (int jj = 0; jj < 4; ++jj)
#pragma unroll
        for (int nn = 0; nn < 4; ++nn) acc[jj][nn] = 0.0f;

#pragma unroll 2
    for (int kk = 0; kk < 32; ++kk) {
        int k = kk * 4;
        float4 w[4], v4[4];
#pragma unroll
        for (int jj = 0; jj < 4; ++jj)
            w[jj] = *(const float4*)(Wl + (ty + jj * 16) * LDS_STRIDE + k);
#pragma unroll
        for (int nn = 0; nn < 4; ++nn)
            v4[nn] = *(const float4*)(Tl + (tx + nn * 16) * LDS_STRIDE + k);
#pragma unroll
        for (int jj = 0; jj < 4; ++jj)
#pragma unroll
            for (int nn = 0; nn < 4; ++nn)
                acc[jj][nn] += w[jj].x * v4[nn].x + w[jj].y * v4[nn].y +
                               w[jj].z * v4[nn].z + w[jj].w * v4[nn].w;
    }

    // epilogue: relu + sum over this thread's 4 n, reduce over tx, atomic
#pragma unroll
    for (int jj = 0; jj < 4; ++jj) {
        float s = 0.0f;
#pragma unroll
        for (int nn = 0; nn < 4; ++nn) s += fmaxf(acc[jj][nn] + bj[jj], 0.0f);
        s += __shfl_xor(s, 1);
        s += __shfl_xor(s, 2);
        s += __shfl_xor(s, 4);
        s += __shfl_xor(s, 8);
        if (tx == 0) atomicAdd(&g_accum[j0 + ty + jj * 16], s);
    }
}

// ---------------------------------------------------------------
// K4: heads. g = g_accum/N; actor & critic MLPs; softmax; value.
// ---------------------------------------------------------------
__global__ __launch_bounds__(256) void k_heads(const float* __restrict__ g_accum,
                                               const float* __restrict__ W_a1,
                                               const float* __restrict__ b_a1,
                                               const float* __restrict__ W_a2,
                                               const float* __restrict__ b_a2,
                                               const float* __restrict__ W_c1,
                                               const float* __restrict__ b_c1,
                                               const float* __restrict__ W_c2,
                                               const float* __restrict__ b_c2,
                                               float* __restrict__ out) {
    __shared__ float gv[H_DIM];
    __shared__ float ah[128];   // actor hidden
    __shared__ float ch[128];   // critic hidden
    int tid = threadIdx.x;

    gv[tid] = g_accum[tid] * (1.0f / (float)N_NODES);
    __syncthreads();

    if (tid < 128) {
        float acc = b_a1[tid];
        const float* wr = W_a1 + tid * H_DIM;
        for (int k = 0; k < H_DIM; ++k) acc += wr[k] * gv[k];
        ah[tid] = fmaxf(acc, 0.0f);
    } else {
        int i = tid - 128;
        float acc = b_c1[i];
        const float* wr = W_c1 + i * H_DIM;
        for (int k = 0; k < H_DIM; ++k) acc += wr[k] * gv[k];
        ch[i] = fmaxf(acc, 0.0f);
    }
    __syncthreads();

    if (tid < 64) {
        float acc = b_a2[tid];
        const float* wr = W_a2 + tid * 128;
        for (int i = 0; i < 128; ++i) acc += wr[i] * ah[i];
        float m = acc;
        for (int off = 32; off; off >>= 1) m = fmaxf(m, __shfl_xor(m, off));
        float e = expf(acc - m);
        float s = e;
        for (int off = 32; off; off >>= 1) s += __shfl_xor(s, off);
        out[tid] = e / s;
    } else if (tid < 128) {
        int l = tid - 64;
        float acc = 0.0f;
        for (int i = l; i < 128; i += 64) acc += W_c2[i] * ch[i];
        for (int off = 32; off; off >>= 1) acc += __shfl_xor(acc, off);
        if (l == 0) out[A_DIM] = acc + b_c2[0];
    }
}

// ---------------------------------------------------------------
extern "C" void kernel_launch(void* const* d_in, const int* in_sizes, int n_in,
                              void* d_out, int out_size, void* d_ws, size_t ws_size,
                              hipStream_t stream) {
    const float* X    = (const float*)d_in[0];
    const int*   ei   = (const int*)d_in[1];
    const float* Wg   = (const float*)d_in[2];
    const float* bg   = (const float*)d_in[3];
    const float* W_a1 = (const float*)d_in[4];
    const float* b_a1 = (const float*)d_in[5];
    const float* W_a2 = (const float*)d_in[6];
    const float* b_a2 = (const float*)d_in[7];
    const float* W_c1 = (const float*)d_in[8];
    const float* b_c1 = (const float*)d_in[9];
    const float* W_c2 = (const float*)d_in[10];
    const float* b_c2 = (const float*)d_in[11];
    float* out = (float*)d_out;

    uint8_t*  ws     = (uint8_t*)d_ws;
    uint32_t* bitmap = (uint32_t*)ws;
    float*    g_acc  = (float*)(ws + GACC_OFF);
    float*    t      = (float*)(ws + T_OFF);

    hipMemsetAsync(d_ws, 0, BITMAP_BYTES + 1024, stream);

    k_scatter<<<E_EDGES / 256, 256, 0, stream>>>(ei, bitmap);
    k_gather <<<N_NODES / 4, 256, 0, stream>>>(X, bitmap, t);
    k_gemm   <<<1024, 256, 0, stream>>>(t, Wg, bg, g_acc);
    k_heads  <<<1, 256, 0, stream>>>(g_acc, W_a1, b_a1, W_a2, b_a2,
                                     W_c1, b_c1, W_c2, b_c2, out);
}

// Round 10
// 184.452 us; speedup vs baseline: 2.7666x; 1.0195x over previous
//
#include <hip/hip_runtime.h>
#include <stdint.h>

// Problem constants (from reference)
#define N_NODES 16384
#define E_EDGES 524288
#define F_INF   128      // node feature dim
#define H_DIM   256      // hidden dim
#define A_DIM   64       // action size
#define BCAP    128      // bucket capacity per source (Poisson(32) tail ~1e-40)

// ---------------- ws layout ----------------
// [0, 64KB)   : cnt uint32[16384]      (zeroed each launch)
// [64KB,+1KB) : g_accum float[256]     (zeroed each launch)
// [80KB, +4MB): bucket uint16[N][BCAP]
// [then]      : t float[N][128]
#define CNT_OFF    0
#define GACC_OFF   (64 * 1024)
#define BUCKET_OFF (80 * 1024)
#define T_OFF      (BUCKET_OFF + (size_t)N_NODES * BCAP * 2)

// ---------------------------------------------------------------
// K1: bucketed adjacency-list build (replaces 33.5MB bitmap+memset
// +scatter of R2-R7). slot=atomicAdd(cnt[s]) gives both position
// and final count. Counters 64KB (L2-hot), buckets 4MB.
// Dup edges kept here; dedup happens in k_gather's LDS bitmap.
// ---------------------------------------------------------------
__global__ __launch_bounds__(256) void k_fill(const int* __restrict__ ei,
                                              uint32_t* __restrict__ cnt,
                                              uint16_t* __restrict__ bucket) {
    int e = blockIdx.x * 256 + threadIdx.x;
    int s = ei[e];              // edge_index[0][e]
    int d = ei[E_EDGES + e];    // edge_index[1][e]
    uint32_t slot = atomicAdd(&cnt[s], 1u);
    if (slot < BCAP) bucket[(size_t)s * BCAP + slot] = (uint16_t)d;
}

// ---------------------------------------------------------------
// K2: one wave per node. Exact set-dedup via per-wave 2KB LDS
// bitmap (atomicOr returns old bit -> first-seen wins), ballot+
// popc compaction into a wave queue, then batched MLP=8 float2
// gathers (R6-proven phase B). deg = 1 + unique count (incl self
// if self-edge present -> X[n] coefficient 2, matching adj + I).
// ---------------------------------------------------------------
__global__ __launch_bounds__(256) void k_gather(const float* __restrict__ X,
                                                const uint32_t* __restrict__ cnt,
                                                const uint16_t* __restrict__ bucket,
                                                float* __restrict__ t) {
    __shared__ uint32_t bmp[4][512];    // 16384 bits per wave = 8KB total
    __shared__ uint16_t q[4][BCAP];     // 1KB total
    int wid  = threadIdx.x >> 6;
    int lane = threadIdx.x & 63;
    int n    = blockIdx.x * 4 + wid;
    uint32_t* mybm = bmp[wid];
    uint16_t* myq  = q[wid];
    const float2* X2 = (const float2*)X;

    // clear this wave's bitmap (512 words / 64 lanes = 8 each)
#pragma unroll
    for (int i = 0; i < 8; ++i) mybm[lane + i * 64] = 0u;

    int m = (int)cnt[n];
    if (m > BCAP) m = BCAP;
    const uint16_t* list = bucket + (size_t)n * BCAP;

    // dedup + compact (m <= 128 -> at most 2 rounds)
    int qn = 0;
    for (int base = 0; base < m; base += 64) {
        int idx = base + lane;
        int d = 0;
        bool keep = false;
        if (idx < m) {
            d = list[idx];
            uint32_t bit = 1u << (d & 31);
            uint32_t old = atomicOr(&mybm[d >> 5], bit);
            keep = !(old & bit);
        }
        unsigned long long mask = __ballot(keep);
        int pos = qn + __popcll(mask & ((1ull << lane) - 1ull));
        if (keep) myq[pos] = (uint16_t)d;
        qn += __popcll(mask);
    }

    // ---- batched gather, MLP=8 (same-wave LDS, no barrier needed) ----
    float2 a = X2[(size_t)n * 64 + lane];       // identity term
    int cdeg = 1 + qn;                          // eye + unique neighbors

    const uint64_t* q8 = (const uint64_t*)myq;  // 4 ids per read
    int i = 0;
    for (; i + 8 <= qn; i += 8) {
        uint64_t p0 = q8[(i >> 2)];
        uint64_t p1 = q8[(i >> 2) + 1];
        int d0 = (int)(p0 & 0xFFFF), d1 = (int)((p0 >> 16) & 0xFFFF);
        int d2 = (int)((p0 >> 32) & 0xFFFF), d3 = (int)(p0 >> 48);
        int d4 = (int)(p1 & 0xFFFF), d5 = (int)((p1 >> 16) & 0xFFFF);
        int d6 = (int)((p1 >> 32) & 0xFFFF), d7 = (int)(p1 >> 48);
        float2 v0 = X2[(size_t)d0 * 64 + lane];
        float2 v1 = X2[(size_t)d1 * 64 + lane];
        float2 v2 = X2[(size_t)d2 * 64 + lane];
        float2 v3 = X2[(size_t)d3 * 64 + lane];
        float2 v4 = X2[(size_t)d4 * 64 + lane];
        float2 v5 = X2[(size_t)d5 * 64 + lane];
        float2 v6 = X2[(size_t)d6 * 64 + lane];
        float2 v7 = X2[(size_t)d7 * 64 + lane];
        a.x += ((v0.x + v1.x) + (v2.x + v3.x)) + ((v4.x + v5.x) + (v6.x + v7.x));
        a.y += ((v0.y + v1.y) + (v2.y + v3.y)) + ((v4.y + v5.y) + (v6.y + v7.y));
    }
    for (; i < qn; ++i) {
        int d = myq[i];
        float2 v = X2[(size_t)d * 64 + lane];
        a.x += v.x;
        a.y += v.y;
    }

    float inv = 1.0f / (float)cdeg;
    float2 r;
    r.x = a.x * inv;
    r.y = a.y * inv;
    ((float2*)t)[(size_t)n * 64 + lane] = r;
}

// ---------------------------------------------------------------
// K3: tiled SGEMM + fused relu/column-sum.
// C[j][n] = W[j]·t[n];  g_acc[j] += sum_n relu(C + b[j]).
// Block tile 64j x 64n, K=128 staged once. Thread tile 4j x 4n.
// *** #pragma unroll 2 on the K loop is load-pressure control: R4's
// full unroll let the scheduler hoist all 256 ds_reads -> 256 VGPR,
// ~940MB scratch spill traffic, 354us. Window of 2 keeps <=16 live
// float4 loads. R6/R7: out of top-5 (<40us). ***
// LDS rows padded to 132 floats (<=2-way bank aliasing = free).
// Epilogue: relu, shfl-reduce over tx, 64 atomics/block.
// ---------------------------------------------------------------
#define LDS_STRIDE 132
__global__ __launch_bounds__(256, 2) void k_gemm(const float* __restrict__ t,
                                                 const float* __restrict__ Wg,
                                                 const float* __restrict__ bg,
                                                 float* __restrict__ g_accum) {
    __shared__ __align__(16) float Wl[64 * LDS_STRIDE];   // 33.8 KB
    __shared__ __align__(16) float Tl[64 * LDS_STRIDE];   // 33.8 KB

    int tid = threadIdx.x;
    int bid = blockIdx.x;
    // XCD-contiguous remap: 1024 blocks, 8 XCDs, 128 blocks each.
    int v  = (bid >> 3) + (bid & 7) * 128;
    int jt = v & 3, nt = v >> 2;
    int j0 = jt * 64, n0 = nt * 64;

    // cooperative coalesced stage of both tiles
#pragma unroll
    for (int i = tid; i < 64 * 32; i += 256) {
        int r = i >> 5, c = i & 31;
        ((float4*)(Wl + r * LDS_STRIDE))[c] =
            ((const float4*)(Wg + (size_t)(j0 + r) * F_INF))[c];
        ((float4*)(Tl + r * LDS_STRIDE))[c] =
            ((const float4*)(t + (size_t)(n0 + r) * F_INF))[c];
    }

    int ty = tid >> 4, tx = tid & 15;
    float bj[4];
#pragma unroll
    for (int jj = 0; jj < 4; ++jj) bj[jj] = bg[j0 + ty + jj * 16];

    __syncthreads();

    float acc[4][4];
#pragma unroll
    for (int jj = 0; jj < 4; ++jj)
#pragma unroll
        for (int nn = 0; nn < 4; ++nn) acc[jj][nn] = 0.0f;

#pragma unroll 2
    for (int kk = 0; kk < 32; ++kk) {
        int k = kk * 4;
        float4 w[4], v4[4];
#pragma unroll
        for (int jj = 0; jj < 4; ++jj)
            w[jj] = *(const float4*)(Wl + (ty + jj * 16) * LDS_STRIDE + k);
#pragma unroll
        for (int nn = 0; nn < 4; ++nn)
            v4[nn] = *(const float4*)(Tl + (tx + nn * 16) * LDS_STRIDE + k);
#pragma unroll
        for (int jj = 0; jj < 4; ++jj)
#pragma unroll
            for (int nn = 0; nn < 4; ++nn)
                acc[jj][nn] += w[jj].x * v4[nn].x + w[jj].y * v4[nn].y +
                               w[jj].z * v4[nn].z + w[jj].w * v4[nn].w;
    }

    // epilogue: relu + sum over this thread's 4 n, reduce over tx, atomic
#pragma unroll
    for (int jj = 0; jj < 4; ++jj) {
        float s = 0.0f;
#pragma unroll
        for (int nn = 0; nn < 4; ++nn) s += fmaxf(acc[jj][nn] + bj[jj], 0.0f);
        s += __shfl_xor(s, 1);
        s += __shfl_xor(s, 2);
        s += __shfl_xor(s, 4);
        s += __shfl_xor(s, 8);
        if (tx == 0) atomicAdd(&g_accum[j0 + ty + jj * 16], s);
    }
}

// ---------------------------------------------------------------
// K4: heads. g = g_accum/N; actor & critic MLPs; softmax; value.
// ---------------------------------------------------------------
__global__ __launch_bounds__(256) void k_heads(const float* __restrict__ g_accum,
                                               const float* __restrict__ W_a1,
                                               const float* __restrict__ b_a1,
                                               const float* __restrict__ W_a2,
                                               const float* __restrict__ b_a2,
                                               const float* __restrict__ W_c1,
                                               const float* __restrict__ b_c1,
                                               const float* __restrict__ W_c2,
                                               const float* __restrict__ b_c2,
                                               float* __restrict__ out) {
    __shared__ float gv[H_DIM];
    __shared__ float ah[128];   // actor hidden
    __shared__ float ch[128];   // critic hidden
    int tid = threadIdx.x;

    gv[tid] = g_accum[tid] * (1.0f / (float)N_NODES);
    __syncthreads();

    if (tid < 128) {
        float acc = b_a1[tid];
        const float* wr = W_a1 + tid * H_DIM;
        for (int k = 0; k < H_DIM; ++k) acc += wr[k] * gv[k];
        ah[tid] = fmaxf(acc, 0.0f);
    } else {
        int i = tid - 128;
        float acc = b_c1[i];
        const float* wr = W_c1 + i * H_DIM;
        for (int k = 0; k < H_DIM; ++k) acc += wr[k] * gv[k];
        ch[i] = fmaxf(acc, 0.0f);
    }
    __syncthreads();

    if (tid < 64) {
        float acc = b_a2[tid];
        const float* wr = W_a2 + tid * 128;
        for (int i = 0; i < 128; ++i) acc += wr[i] * ah[i];
        float m = acc;
        for (int off = 32; off; off >>= 1) m = fmaxf(m, __shfl_xor(m, off));
        float e = expf(acc - m);
        float s = e;
        for (int off = 32; off; off >>= 1) s += __shfl_xor(s, off);
        out[tid] = e / s;
    } else if (tid < 128) {
        int l = tid - 64;
        float acc = 0.0f;
        for (int i = l; i < 128; i += 64) acc += W_c2[i] * ch[i];
        for (int off = 32; off; off >>= 1) acc += __shfl_xor(acc, off);
        if (l == 0) out[A_DIM] = acc + b_c2[0];
    }
}

// ---------------------------------------------------------------
extern "C" void kernel_launch(void* const* d_in, const int* in_sizes, int n_in,
                              void* d_out, int out_size, void* d_ws, size_t ws_size,
                              hipStream_t stream) {
    const float* X    = (const float*)d_in[0];
    const int*   ei   = (const int*)d_in[1];
    const float* Wg   = (const float*)d_in[2];
    const float* bg   = (const float*)d_in[3];
    const float* W_a1 = (const float*)d_in[4];
    const float* b_a1 = (const float*)d_in[5];
    const float* W_a2 = (const float*)d_in[6];
    const float* b_a2 = (const float*)d_in[7];
    const float* W_c1 = (const float*)d_in[8];
    const float* b_c1 = (const float*)d_in[9];
    const float* W_c2 = (const float*)d_in[10];
    const float* b_c2 = (const float*)d_in[11];
    float* out = (float*)d_out;

    uint8_t*  ws     = (uint8_t*)d_ws;
    uint32_t* cnt    = (uint32_t*)(ws + CNT_OFF);
    float*    g_acc  = (float*)(ws + GACC_OFF);
    uint16_t* bucket = (uint16_t*)(ws + BUCKET_OFF);
    float*    t      = (float*)(ws + T_OFF);

    // zero counters + g_accum only (65.5KB, was 33.5MB in R2-R7)
    hipMemsetAsync(ws, 0, GACC_OFF + 1024, stream);

    k_fill  <<<E_EDGES / 256, 256, 0, stream>>>(ei, cnt, bucket);
    k_gather<<<N_NODES / 4, 256, 0, stream>>>(X, cnt, bucket, t);
    k_gemm  <<<1024, 256, 0, stream>>>(t, Wg, bg, g_acc);
    k_heads <<<1, 256, 0, stream>>>(g_acc, W_a1, b_a1, W_a2, b_a2,
                                    W_c1, b_c1, W_c2, b_c2, out);
}